// Round 5
// baseline (4470.711 us; speedup 1.0000x reference)
//
#include <hip/hip_runtime.h>

// ---------------- problem constants ----------------
#define Hd   256
#define Bd   16
#define Td   128
#define Ld   50
#define Vd   32000
#define G5H  1280     // 5*H

typedef __attribute__((ext_vector_type(8))) short short8v;  // 8 bf16 (4 VGPRs)
typedef __attribute__((ext_vector_type(4))) float f32x4;

__device__ __forceinline__ unsigned short f2bu(float f) {   // f32 -> bf16 bits (RNE)
  unsigned u = __float_as_uint(f);
  unsigned r = (u + 0x7fffu + ((u >> 16) & 1u)) >> 16;
  return (unsigned short)r;
}
__device__ __forceinline__ float bu2f(unsigned short b) {
  return __uint_as_float(((unsigned)b) << 16);
}
__device__ __forceinline__ float sigm(float x) { return 1.f / (1.f + __expf(-x)); }

// ---------------- fp32 -> bf16 conversion + MFMA fragment packing ----------------
// Plain bf16 copies: wv, w_ih, fcW (row-major, used by LDS-staged GEMMs).
// Fragment-ordered bf16: w_hh, Z, P. Fragment (T,ks) = 512 shorts laid out so
// lane L of a wave reads shorts [frag*512 + L*8 .. +8) = mat[T*16 + (L&15)]
// [ks*32 + (L>>4)*8 .. +8)  -> every A-load is one coalesced 1KB stream.
__global__ __launch_bounds__(256) void conv_kernel(
    const float* __restrict__ wv, const float* __restrict__ w_ih,
    const float* __restrict__ fcW, const float* __restrict__ w_hh,
    const float* __restrict__ Zm, const float* __restrict__ Pm,
    unsigned short* __restrict__ wv_b, unsigned short* __restrict__ wih_b,
    unsigned short* __restrict__ fcw_b, unsigned short* __restrict__ whh_f,
    unsigned short* __restrict__ z_f, unsigned short* __restrict__ p_f)
{
  const long N0 = 2048000, N1 = N0 + 81920, N2 = N1 + 2048000;
  const long NW = 81920, NZ = 16384, NP = 16384;         // frag float4-groups
  const long N5 = N2 + NW + NZ + NP;
  for (long idx = (long)blockIdx.x * blockDim.x + threadIdx.x; idx < N5;
       idx += (long)gridDim.x * blockDim.x) {
    if (idx < N2) {                                      // plain copies
      const float* src; unsigned short* dst; long off;
      if      (idx < N0) { src = wv;   dst = wv_b;  off = idx; }
      else if (idx < N1) { src = w_ih; dst = wih_b; off = idx - N0; }
      else               { src = fcW;  dst = fcw_b; off = idx - N1; }
      float4 v = *(const float4*)(src + off * 4);
      ushort4 o;
      o.x = f2bu(v.x); o.y = f2bu(v.y); o.z = f2bu(v.z); o.w = f2bu(v.w);
      *(ushort4*)(dst + off * 4) = o;
    } else {                                             // fragment packing
      long u = idx - N2;
      const float* src; unsigned short* dst;
      if      (u < NW)      { src = w_hh; dst = whh_f; }
      else if (u < NW + NZ) { src = Zm;   dst = z_f;  u -= NW; }
      else                  { src = Pm;   dst = p_f;  u -= NW + NZ; }
      long frag = u >> 7;                 // 128 float4-groups per 512-short frag
      int g128 = (int)(u & 127);
      int lane = g128 >> 1, e0 = (g128 & 1) * 4;
      long T = frag >> 3; int ks = (int)(frag & 7);
      int lr = lane & 15, lg = lane >> 4;
      float4 v = *(const float4*)(src + (T * 16 + lr) * 256 + ks * 32 + lg * 8 + e0);
      ushort4 o;
      o.x = f2bu(v.x); o.y = f2bu(v.y); o.z = f2bu(v.z); o.w = f2bu(v.w);
      *(ushort4*)(dst + u * 4) = o;
    }
  }
}

// ---------------- per-batch prep: goal embed, ht0, goal_term, E, sumE ----------------
__global__ __launch_bounds__(256) void prep_kernel(
    const int* __restrict__ g, const int* __restrict__ ingr,
    const float* __restrict__ wv, const float* __restrict__ Ug,
    const float* __restrict__ Ym, const float* __restrict__ yb,
    float* __restrict__ E_ws, float* __restrict__ sumE,
    float* __restrict__ goal_ws, float* __restrict__ HT0)
{
  __shared__ float ge[256];
  const int b = blockIdx.x, tid = threadIdx.x;
  float s = 0.f;
  for (int i = 0; i < 8; ++i) s += wv[((size_t)g[(b << 3) + i] << 8) + tid];
  ge[tid] = s;
  __syncthreads();
  float h0 = 0.f, gt = 0.f;
  const float* ur = Ug + (tid << 8);
  const float* yr = Ym + (tid << 8);
#pragma unroll 8
  for (int k = 0; k < Hd; k += 4) {
    float4 gv = *(const float4*)(ge + k);
    float4 uv = *(const float4*)(ur + k);
    float4 yv = *(const float4*)(yr + k);
    h0 = fmaf(gv.x, uv.x, h0); h0 = fmaf(gv.y, uv.y, h0);
    h0 = fmaf(gv.z, uv.z, h0); h0 = fmaf(gv.w, uv.w, h0);
    gt = fmaf(gv.x, yv.x, gt); gt = fmaf(gv.y, yv.y, gt);
    gt = fmaf(gv.z, yv.z, gt); gt = fmaf(gv.w, yv.w, gt);
  }
  HT0[(b << 8) + tid] = h0;                    // [b][c]
  goal_ws[(b << 8) + tid] = gt + yb[tid];      // [b][c]
  float se = 0.f;
  for (int l = 0; l < Ld; ++l) {
    float v = wv[((size_t)ingr[b * Ld + l] << 8) + tid];
    E_ws[((size_t)(b * Ld + l) << 8) + tid] = v;
    se += v;
  }
  sumE[(b << 8) + tid] = se;                   // [b][k]
}

// ---------------- bf16 MFMA GEMM (128x128 tile, K=256), two epilogues ----------------
template <int MODE>
__global__ __launch_bounds__(256) void gemm_bf16(
    const unsigned short* __restrict__ A, const unsigned short* __restrict__ Bmat,
    const int* __restrict__ ridx, const float* __restrict__ bias,
    float* __restrict__ C)
{
  __shared__ unsigned short As[128 * 64];
  __shared__ unsigned short Bs[128 * 64];
  const int tid = threadIdx.x;
  const int m0 = blockIdx.x << 7, n0 = blockIdx.y << 7;
  const int wave = tid >> 6, lane = tid & 63;
  const int wm = wave >> 1, wn = wave & 1;
  const int lr = lane & 15, lg = lane >> 4;

  f32x4 acc[4][4];
#pragma unroll
  for (int i = 0; i < 4; ++i)
#pragma unroll
    for (int jj = 0; jj < 4; ++jj) acc[i][jj] = (f32x4){0.f, 0.f, 0.f, 0.f};

  const int srow = tid >> 1, shalf = tid & 1;
  const unsigned short* arow;
  {
    int gm = m0 + srow;
    if (MODE == 0) {
      int tt = gm >> 4, bb = gm & 15;
      arow = A + (size_t)ridx[bb * Td + tt] * Hd;
    } else {
      arow = A + (size_t)gm * Hd;
    }
  }
  const unsigned short* brow = Bmat + (size_t)(n0 + srow) * Hd;

  for (int k0 = 0; k0 < Hd; k0 += 64) {
#pragma unroll
    for (int c = 0; c < 4; ++c) {
      int k = shalf * 32 + c * 8;
      uint4 va = *(const uint4*)(arow + k0 + k);
      uint4 vb = *(const uint4*)(brow + k0 + k);
      int byo = (srow << 7) + ((k << 1) ^ ((srow & 7) << 4));  // XOR swizzle
      *(uint4*)((char*)As + byo) = va;
      *(uint4*)((char*)Bs + byo) = vb;
    }
    __syncthreads();
#pragma unroll
    for (int kk = 0; kk < 2; ++kk) {
      short8v af[4], bfr[4];
      const int kb = kk * 32 + lg * 8;
#pragma unroll
      for (int i = 0; i < 4; ++i) {
        int ar = wm * 64 + i * 16 + lr;
        af[i] = *(const short8v*)((const char*)As + (ar << 7) + ((kb << 1) ^ ((ar & 7) << 4)));
        int br = wn * 64 + i * 16 + lr;
        bfr[i] = *(const short8v*)((const char*)Bs + (br << 7) + ((kb << 1) ^ ((br & 7) << 4)));
      }
#pragma unroll
      for (int i = 0; i < 4; ++i)
#pragma unroll
        for (int jj = 0; jj < 4; ++jj)
          acc[i][jj] = __builtin_amdgcn_mfma_f32_16x16x32_bf16(af[i], bfr[jj], acc[i][jj], 0, 0, 0);
    }
    __syncthreads();
  }
#pragma unroll
  for (int i = 0; i < 4; ++i)
#pragma unroll
    for (int jj = 0; jj < 4; ++jj) {
      int col = n0 + wn * 64 + jj * 16 + lr;
      float bv = bias[col];
#pragma unroll
      for (int r = 0; r < 4; ++r) {
        int row = m0 + wm * 64 + i * 16 + lg * 4 + r;
        float v = acc[i][jj][r] + bv;
        if (MODE == 0) {
          int tt = row >> 4, bb = row & 15;
          C[((size_t)(bb * Td + tt)) * G5H + col] = v;   // gi[b][t][grow]
        } else {
          C[(size_t)row * Vd + col] = v;
        }
      }
    }
}

// ---------------- recurrence kernel v5: wave-resident weights, 16 waves ----------------
// One WG per batch. Each wave holds 64 weight fragments (256 VGPRs) permanently:
// waves 0-9 w_hh (tiles wid*8..+8), waves 10-11 Z, waves 12-13 P (14-15 dup).
// B-operand packs ht_hi in MFMA col 0 and ht_lo in col 1; gh = D[:,0]+D[:,1]
// via shfl_xor(.,1). Zero global weight traffic inside the t-loop.
__global__ __launch_bounds__(1024, 1) void rnn_kernel(
    const unsigned short* __restrict__ whh_f, const unsigned short* __restrict__ z_f,
    const unsigned short* __restrict__ p_f, const float* __restrict__ b_hh,
    const float* __restrict__ Sm, const float* __restrict__ z_bias,
    const float* __restrict__ gi, const float* __restrict__ goal_ws,
    const float* __restrict__ E_ws, const float* __restrict__ sumE,
    const float* __restrict__ HT0,
    unsigned short* __restrict__ out_all, float* __restrict__ d_out)
{
  __shared__ float gh_lds[1280];
  __shared__ float zd_lds[256];
  __shared__ float hp_lds[256];
  __shared__ float hrow[256];                       // fp32 ht (current)
  __shared__ __align__(16) unsigned short ht_hi[256];
  __shared__ __align__(16) unsigned short ht_lo[256];
  __shared__ __align__(16) unsigned short tp_hi[256];
  __shared__ __align__(16) unsigned short tp_lo[256];
  __shared__ float se_lds[256], gl_lds[256], bh_lds[1280], zb_lds[256];
  __shared__ __align__(16) unsigned short E_lds[Ld * 264];
  __shared__ float a_lds[64], d_lds[64], an_lds[64], au_lds[64];
  __shared__ float sd_lds[4], ref_lds[4];

  const int b = blockIdx.x;
  const int tid = threadIdx.x;
  const int lane = tid & 63, wid = tid >> 6;
  const int lr = lane & 15, lg = lane >> 4;

  // ---- wave-resident weight fragments (loaded once, live whole kernel) ----
  const unsigned short* gb;
  if      (wid < 10) gb = whh_f + (((size_t)wid * 64) << 9);
  else if (wid < 12) gb = z_f + (((size_t)(wid - 10) * 64) << 9);
  else               gb = p_f + (((size_t)((wid - 12) & 1) * 64) << 9);
  short8v W[64];
#pragma unroll
  for (int f = 0; f < 64; ++f)
    W[f] = *(const short8v*)(gb + (((size_t)f) << 9) + (lane << 3));

  // ---- one-time LDS staging ----
  for (int idx = tid; idx < Ld * 256; idx += 1024) {
    int l = idx >> 8, k = idx & 255;
    E_lds[l * 264 + k] = f2bu(E_ws[((size_t)(b * Ld + l) << 8) + k]);
  }
  for (int idx = tid; idx < 1280; idx += 1024) bh_lds[idx] = b_hh[idx];
  if (tid < 256) {
    float se = sumE[(b << 8) + tid];
    se_lds[tid] = se;
    unsigned short hi = f2bu(se);
    tp_hi[tid] = hi; tp_lo[tid] = f2bu(se - bu2f(hi));
    gl_lds[tid] = goal_ws[(b << 8) + tid];
    zb_lds[tid] = z_bias[tid];
    float h0 = HT0[(b << 8) + tid];
    hrow[tid] = h0;
    unsigned short h0h = f2bu(h0);
    ht_hi[tid] = h0h; ht_lo[tid] = f2bu(h0 - bu2f(h0h));
  }
  if (tid < 64) a_lds[tid] = 0.f;
  __syncthreads();

  for (int t = 0; t < Td; ++t) {
    // ---- prefetch gi(t): latency hides under phase A ----
    float pre_ir = 0.f, pre_iu = 0.f, pre_in = 0.f, pre_ig = 0.f, pre_ii = 0.f;
    if (tid < 256) {
      const float* gib = gi + ((size_t)(b * Td + t)) * G5H + tid;
      pre_ir = gib[0];    pre_iu = gib[256];  pre_in = gib[512];
      pre_ig = gib[768];  pre_ii = gib[1024];
    }
    // ========== phase A: gh (waves 0-9) + zd (waves 10-11), reg-resident MFMA ==========
    if (wid < 12) {
      f32x4 acc[8];
#pragma unroll
      for (int i = 0; i < 8; ++i) acc[i] = (f32x4){0.f, 0.f, 0.f, 0.f};
      const unsigned short* src_hi = (wid < 10) ? ht_hi : tp_hi;
      const unsigned short* src_lo = (wid < 10) ? ht_lo : tp_lo;
#pragma unroll
      for (int ks = 0; ks < 8; ++ks) {
        short8v bb = {0,0,0,0,0,0,0,0};
        if (lr < 2)
          bb = *(const short8v*)((lr == 0 ? src_hi : src_lo) + ks * 32 + (lg << 3));
#pragma unroll
        for (int i = 0; i < 8; ++i)
          acc[i] = __builtin_amdgcn_mfma_f32_16x16x32_bf16(W[i * 8 + ks], bb, acc[i], 0, 0, 0);
      }
#pragma unroll
      for (int i = 0; i < 8; ++i)
#pragma unroll
        for (int r = 0; r < 4; ++r) {
          float v = acc[i][r] + __shfl_xor(acc[i][r], 1);   // col0(hi) + col1(lo)
          if (lr == 0) {
            int row = i * 16 + lg * 4 + r;
            if (wid < 10) gh_lds[wid * 128 + row] = v;
            else          zd_lds[(wid - 10) * 128 + row] = v;
          }
        }
    }
    __syncthreads();
    // ========== phase B: gates -> ht2 ==========
    if (tid < 256) {
      int c = tid;
      float hr = gh_lds[c]        + bh_lds[c];
      float hu = gh_lds[256 + c]  + bh_lds[256 + c];
      float hn = gh_lds[512 + c]  + bh_lds[512 + c];
      float hg = gh_lds[768 + c]  + bh_lds[768 + c];
      float hq = gh_lds[1024 + c] + bh_lds[1024 + c];
      float rt = sigm(pre_ir + hr), zt = sigm(pre_iu + hu);
      float st = sigm(pre_ig + hg), qt = sigm(pre_ii + hq);
      float htl = tanhf(pre_in + rt * hn + st * gl_lds[c] + qt * (zd_lds[c] + zb_lds[c]));
      float prev = hrow[c];
      float h2 = htl + zt * (prev - htl);
      hrow[c] = h2;
      unsigned short hi = f2bu(h2);
      ht_hi[c] = hi; ht_lo[c] = f2bu(h2 - bu2f(hi));
    }
    __syncthreads();
    // ========== phase C: h_proj (waves 12-13) + S-dots (waves 8-10) ==========
    if (wid >= 12 && wid < 14) {
      f32x4 acc[8];
#pragma unroll
      for (int i = 0; i < 8; ++i) acc[i] = (f32x4){0.f, 0.f, 0.f, 0.f};
#pragma unroll
      for (int ks = 0; ks < 8; ++ks) {
        short8v bb = {0,0,0,0,0,0,0,0};
        if (lr < 2)
          bb = *(const short8v*)((lr == 0 ? ht_hi : ht_lo) + ks * 32 + (lg << 3));
#pragma unroll
        for (int i = 0; i < 8; ++i)
          acc[i] = __builtin_amdgcn_mfma_f32_16x16x32_bf16(W[i * 8 + ks], bb, acc[i], 0, 0, 0);
      }
#pragma unroll
      for (int i = 0; i < 8; ++i)
#pragma unroll
        for (int r = 0; r < 4; ++r) {
          float v = acc[i][r] + __shfl_xor(acc[i][r], 1);
          if (lr == 0)
            hp_lds[(wid - 12) * 128 + i * 16 + lg * 4 + r] = v;
        }
    } else if (wid >= 8 && wid < 11) {              // S dots
      int w = wid - 8;
      float4 sv = *(const float4*)(Sm + (w << 8) + (lane << 2));
      float4 hv = *(const float4*)(hrow + (lane << 2));
      float p = sv.x * hv.x + sv.y * hv.y + sv.z * hv.z + sv.w * hv.w;
      p += __shfl_xor(p, 1);  p += __shfl_xor(p, 2);  p += __shfl_xor(p, 4);
      p += __shfl_xor(p, 8);  p += __shfl_xor(p, 16); p += __shfl_xor(p, 32);
      if (lane == 0) sd_lds[w] = p;
    }
    __syncthreads();
    // ========== phase D: E-dots + ref softmax ==========
    if (tid < 200) {
      int l = tid >> 2, q = tid & 3;
      const unsigned short* er = E_lds + l * 264 + (q << 6);
      const float* hq = hp_lds + (q << 6);
      float p = 0.f;
#pragma unroll 8
      for (int i = 0; i < 32; ++i) {
        unsigned uu = *(const unsigned*)(er + 2 * i);
        float e0 = __uint_as_float(uu << 16);
        float e1 = __uint_as_float(uu & 0xffff0000u);
        p = fmaf(e0, hq[2 * i], p);
        p = fmaf(e1, hq[2 * i + 1], p);
      }
      p += __shfl_xor(p, 1); p += __shfl_xor(p, 2);
      if (q == 0) d_lds[l] = p;
    } else if (tid == 960) {                        // ref = softmax(BETA*sd)
      float s0 = 5.0f * sd_lds[0], s1 = 5.0f * sd_lds[1], s2 = 5.0f * sd_lds[2];
      float m = fmaxf(s0, fmaxf(s1, s2));
      float e0 = __expf(s0 - m), e1 = __expf(s1 - m), e2 = __expf(s2 - m);
      float inv = 1.f / (e0 + e1 + e2);
      ref_lds[0] = e0 * inv; ref_lds[1] = e1 * inv; ref_lds[2] = e2 * inv;
    }
    __syncthreads();
    // ========== phase E: alpha_n / alpha_u ==========
    if (tid < 128) {
      int which = tid >> 6;
      int l = tid & 63;
      float dv;
      if (which == 0) dv = (l < Ld) ? 2.0f * (1.f - a_lds[l]) * d_lds[l] : -3.4e38f;
      else            dv = (l < Ld) ? 2.0f * a_lds[l] * d_lds[l]         : -3.4e38f;
      float m = dv;
      m = fmaxf(m, __shfl_xor(m, 1));  m = fmaxf(m, __shfl_xor(m, 2));
      m = fmaxf(m, __shfl_xor(m, 4));  m = fmaxf(m, __shfl_xor(m, 8));
      m = fmaxf(m, __shfl_xor(m, 16)); m = fmaxf(m, __shfl_xor(m, 32));
      float e = (l < Ld) ? __expf(dv - m) : 0.f;
      float ss = e;
      ss += __shfl_xor(ss, 1);  ss += __shfl_xor(ss, 2);  ss += __shfl_xor(ss, 4);
      ss += __shfl_xor(ss, 8);  ss += __shfl_xor(ss, 16); ss += __shfl_xor(ss, 32);
      float al = e / ss;
      if (which == 0) an_lds[l] = al; else au_lds[l] = al;
    }
    __syncthreads();
    // ========== phase F: c_n, c_u, out, tmp(t+1) ==========
    if (tid < 256) {
      int k = tid;
      float accn = 0.f, accu = 0.f, acct = 0.f;
#pragma unroll 10
      for (int l = 0; l < Ld; ++l) {
        float e = bu2f(E_lds[l * 264 + k]);
        accn = fmaf(an_lds[l], e, accn);
        accu = fmaf(au_lds[l], e, accu);
        acct = fmaf(a_lds[l], e, acct);            // a BEFORE this step's update
      }
      float outv = ref_lds[0] * hp_lds[k] + ref_lds[1] * accn + ref_lds[2] * accu;
      out_all[(((b << 7) + t) << 8) + k] = f2bu(outv);
      float tn = se_lds[k] - acct;                 // tmp(t+1) = sum((1-a)*E)
      unsigned short th = f2bu(tn);
      tp_hi[k] = th; tp_lo[k] = f2bu(tn - bu2f(th));
      if (t == Td - 1) {
        d_out[(size_t)65536000 + (b << 8) + k] = hrow[k];
        for (int l = 0; l < Ld; ++l) {             // E_new = (1-a_pre)*E (fp32 source)
          size_t o = ((size_t)(b * Ld + l) << 8) + k;
          d_out[(size_t)65540896 + o] = (1.f - a_lds[l]) * E_ws[o];
        }
      }
    }
    __syncthreads();
    // ========== phase G: a update ==========
    if (tid < Ld) {
      float na = a_lds[tid] + ref_lds[1] * an_lds[tid];
      a_lds[tid] = na;
      if (t == Td - 1) d_out[(size_t)65540096 + b * Ld + tid] = na;
    }
    __syncthreads();
  }
}

// ---------------- host launcher ----------------
extern "C" void kernel_launch(void* const* d_in, const int* in_sizes, int n_in,
                              void* d_out, int out_size, void* d_ws, size_t ws_size,
                              hipStream_t stream)
{
  const int*   recipe = (const int*)d_in[0];
  const int*   g      = (const int*)d_in[1];
  const int*   ingr   = (const int*)d_in[2];
  const float* wv     = (const float*)d_in[3];
  const float* w_ih   = (const float*)d_in[4];
  const float* w_hh   = (const float*)d_in[5];
  const float* b_ih   = (const float*)d_in[6];
  const float* b_hh   = (const float*)d_in[7];
  const float* Z      = (const float*)d_in[8];
  const float* Y      = (const float*)d_in[9];
  const float* Ug     = (const float*)d_in[10];
  const float* z_bias = (const float*)d_in[11];
  const float* y_bias = (const float*)d_in[12];
  const float* S      = (const float*)d_in[13];
  const float* P      = (const float*)d_in[14];
  const float* fcW    = (const float*)d_in[15];
  const float* fcb    = (const float*)d_in[16];
  float* out = (float*)d_out;
  char* ws = (char*)d_ws;

  size_t off = 0;
  unsigned short* wv_b     = (unsigned short*)(ws + off);  off += 16384000;
  unsigned short* wih_b    = (unsigned short*)(ws + off);  off += 655360;
  unsigned short* fcw_b    = (unsigned short*)(ws + off);  off += 16384000;
  unsigned short* whh_f    = (unsigned short*)(ws + off);  off += 655360;
  unsigned short* z_f      = (unsigned short*)(ws + off);  off += 131072;
  unsigned short* p_f      = (unsigned short*)(ws + off);  off += 131072;
  float* gi_ws             = (float*)(ws + off);           off += 10485760;
  float* E_ws              = (float*)(ws + off);           off += 819200;
  float* sumE              = (float*)(ws + off);           off += 16384;
  float* goal_ws           = (float*)(ws + off);           off += 16384;
  float* HT0               = (float*)(ws + off);           off += 16384;
  unsigned short* out_all  = (unsigned short*)(ws + off);  off += 1048576;

  conv_kernel<<<4096, 256, 0, stream>>>(wv, w_ih, fcW, w_hh, Z, P,
                                        wv_b, wih_b, fcw_b, whh_f, z_f, p_f);
  prep_kernel<<<16, 256, 0, stream>>>(g, ingr, wv, Ug, Y, y_bias,
                                      E_ws, sumE, goal_ws, HT0);
  gemm_bf16<0><<<dim3(16, 10), 256, 0, stream>>>(wv_b, wih_b, recipe, b_ih, gi_ws);
  rnn_kernel<<<16, 1024, 0, stream>>>(whh_f, z_f, p_f, b_hh, S, z_bias,
                                      gi_ws, goal_ws, E_ws, sumE, HT0,
                                      out_all, out);
  gemm_bf16<1><<<dim3(16, 250), 256, 0, stream>>>(out_all, fcw_b, nullptr, fcb, out);
}

// Round 6
// 3745.458 us; speedup vs baseline: 1.1936x; 1.1936x over previous
//
#include <hip/hip_runtime.h>

// ---------------- problem constants ----------------
#define Hd   256
#define Bd   16
#define Td   128
#define Ld   50
#define Vd   32000
#define G5H  1280     // 5*H

typedef __attribute__((ext_vector_type(8))) short short8v;  // 8 bf16 (4 VGPRs)
typedef __attribute__((ext_vector_type(4))) float f32x4;

__device__ __forceinline__ unsigned short f2bu(float f) {   // f32 -> bf16 bits (RNE)
  unsigned u = __float_as_uint(f);
  unsigned r = (u + 0x7fffu + ((u >> 16) & 1u)) >> 16;
  return (unsigned short)r;
}
__device__ __forceinline__ float bu2f(unsigned short b) {
  return __uint_as_float(((unsigned)b) << 16);
}
__device__ __forceinline__ float sigm(float x) { return 1.f / (1.f + __expf(-x)); }

// ---------------- fp32 -> bf16 conversion + MFMA fragment packing ----------------
// Plain bf16 copies: wv, w_ih, fcW. Fragment-ordered: w_hh, Z, P.
// Fragment (T,ks) = 512 shorts; lane L reads [frag*512 + L*8) =
// mat[T*16 + (L&15)][ks*32 + (L>>4)*8 .. +8)  -> coalesced 1KB per A-load.
__global__ __launch_bounds__(256) void conv_kernel(
    const float* __restrict__ wv, const float* __restrict__ w_ih,
    const float* __restrict__ fcW, const float* __restrict__ w_hh,
    const float* __restrict__ Zm, const float* __restrict__ Pm,
    unsigned short* __restrict__ wv_b, unsigned short* __restrict__ wih_b,
    unsigned short* __restrict__ fcw_b, unsigned short* __restrict__ whh_f,
    unsigned short* __restrict__ z_f, unsigned short* __restrict__ p_f)
{
  const long N0 = 2048000, N1 = N0 + 81920, N2 = N1 + 2048000;
  const long NW = 81920, NZ = 16384, NP = 16384;         // frag float4-groups
  const long N5 = N2 + NW + NZ + NP;
  for (long idx = (long)blockIdx.x * blockDim.x + threadIdx.x; idx < N5;
       idx += (long)gridDim.x * blockDim.x) {
    if (idx < N2) {                                      // plain copies
      const float* src; unsigned short* dst; long off;
      if      (idx < N0) { src = wv;   dst = wv_b;  off = idx; }
      else if (idx < N1) { src = w_ih; dst = wih_b; off = idx - N0; }
      else               { src = fcW;  dst = fcw_b; off = idx - N1; }
      float4 v = *(const float4*)(src + off * 4);
      ushort4 o;
      o.x = f2bu(v.x); o.y = f2bu(v.y); o.z = f2bu(v.z); o.w = f2bu(v.w);
      *(ushort4*)(dst + off * 4) = o;
    } else {                                             // fragment packing
      long u = idx - N2;
      const float* src; unsigned short* dst;
      if      (u < NW)      { src = w_hh; dst = whh_f; }
      else if (u < NW + NZ) { src = Zm;   dst = z_f;  u -= NW; }
      else                  { src = Pm;   dst = p_f;  u -= NW + NZ; }
      long frag = u >> 7;                 // 128 float4-groups per 512-short frag
      int g128 = (int)(u & 127);
      int lane = g128 >> 1, e0 = (g128 & 1) * 4;
      long T = frag >> 3; int ks = (int)(frag & 7);
      int lr = lane & 15, lg = lane >> 4;
      float4 v = *(const float4*)(src + (T * 16 + lr) * 256 + ks * 32 + lg * 8 + e0);
      ushort4 o;
      o.x = f2bu(v.x); o.y = f2bu(v.y); o.z = f2bu(v.z); o.w = f2bu(v.w);
      *(ushort4*)(dst + u * 4) = o;
    }
  }
}

// ---------------- per-batch prep: goal embed, ht0, goal_term, E, sumE ----------------
__global__ __launch_bounds__(256) void prep_kernel(
    const int* __restrict__ g, const int* __restrict__ ingr,
    const float* __restrict__ wv, const float* __restrict__ Ug,
    const float* __restrict__ Ym, const float* __restrict__ yb,
    float* __restrict__ E_ws, float* __restrict__ sumE,
    float* __restrict__ goal_ws, float* __restrict__ HT0)
{
  __shared__ float ge[256];
  const int b = blockIdx.x, tid = threadIdx.x;
  float s = 0.f;
  for (int i = 0; i < 8; ++i) s += wv[((size_t)g[(b << 3) + i] << 8) + tid];
  ge[tid] = s;
  __syncthreads();
  float h0 = 0.f, gt = 0.f;
  const float* ur = Ug + (tid << 8);
  const float* yr = Ym + (tid << 8);
#pragma unroll 8
  for (int k = 0; k < Hd; k += 4) {
    float4 gv = *(const float4*)(ge + k);
    float4 uv = *(const float4*)(ur + k);
    float4 yv = *(const float4*)(yr + k);
    h0 = fmaf(gv.x, uv.x, h0); h0 = fmaf(gv.y, uv.y, h0);
    h0 = fmaf(gv.z, uv.z, h0); h0 = fmaf(gv.w, uv.w, h0);
    gt = fmaf(gv.x, yv.x, gt); gt = fmaf(gv.y, yv.y, gt);
    gt = fmaf(gv.z, yv.z, gt); gt = fmaf(gv.w, yv.w, gt);
  }
  HT0[(b << 8) + tid] = h0;                    // [b][c]
  goal_ws[(b << 8) + tid] = gt + yb[tid];      // [b][c]
  float se = 0.f;
  for (int l = 0; l < Ld; ++l) {
    float v = wv[((size_t)ingr[b * Ld + l] << 8) + tid];
    E_ws[((size_t)(b * Ld + l) << 8) + tid] = v;
    se += v;
  }
  sumE[(b << 8) + tid] = se;                   // [b][k]
}

// ---------------- bf16 MFMA GEMM (128x128 tile, K=256), two epilogues ----------------
template <int MODE>
__global__ __launch_bounds__(256) void gemm_bf16(
    const unsigned short* __restrict__ A, const unsigned short* __restrict__ Bmat,
    const int* __restrict__ ridx, const float* __restrict__ bias,
    float* __restrict__ C)
{
  __shared__ unsigned short As[128 * 64];
  __shared__ unsigned short Bs[128 * 64];
  const int tid = threadIdx.x;
  const int m0 = blockIdx.x << 7, n0 = blockIdx.y << 7;
  const int wave = tid >> 6, lane = tid & 63;
  const int wm = wave >> 1, wn = wave & 1;
  const int lr = lane & 15, lg = lane >> 4;

  f32x4 acc[4][4];
#pragma unroll
  for (int i = 0; i < 4; ++i)
#pragma unroll
    for (int jj = 0; jj < 4; ++jj) acc[i][jj] = (f32x4){0.f, 0.f, 0.f, 0.f};

  const int srow = tid >> 1, shalf = tid & 1;
  const unsigned short* arow;
  {
    int gm = m0 + srow;
    if (MODE == 0) {
      int tt = gm >> 4, bb = gm & 15;
      arow = A + (size_t)ridx[bb * Td + tt] * Hd;
    } else {
      arow = A + (size_t)gm * Hd;
    }
  }
  const unsigned short* brow = Bmat + (size_t)(n0 + srow) * Hd;

  for (int k0 = 0; k0 < Hd; k0 += 64) {
#pragma unroll
    for (int c = 0; c < 4; ++c) {
      int k = shalf * 32 + c * 8;
      uint4 va = *(const uint4*)(arow + k0 + k);
      uint4 vb = *(const uint4*)(brow + k0 + k);
      int byo = (srow << 7) + ((k << 1) ^ ((srow & 7) << 4));  // XOR swizzle
      *(uint4*)((char*)As + byo) = va;
      *(uint4*)((char*)Bs + byo) = vb;
    }
    __syncthreads();
#pragma unroll
    for (int kk = 0; kk < 2; ++kk) {
      short8v af[4], bfr[4];
      const int kb = kk * 32 + lg * 8;
#pragma unroll
      for (int i = 0; i < 4; ++i) {
        int ar = wm * 64 + i * 16 + lr;
        af[i] = *(const short8v*)((const char*)As + (ar << 7) + ((kb << 1) ^ ((ar & 7) << 4)));
        int br = wn * 64 + i * 16 + lr;
        bfr[i] = *(const short8v*)((const char*)Bs + (br << 7) + ((kb << 1) ^ ((br & 7) << 4)));
      }
#pragma unroll
      for (int i = 0; i < 4; ++i)
#pragma unroll
        for (int jj = 0; jj < 4; ++jj)
          acc[i][jj] = __builtin_amdgcn_mfma_f32_16x16x32_bf16(af[i], bfr[jj], acc[i][jj], 0, 0, 0);
    }
    __syncthreads();
  }
#pragma unroll
  for (int i = 0; i < 4; ++i)
#pragma unroll
    for (int jj = 0; jj < 4; ++jj) {
      int col = n0 + wn * 64 + jj * 16 + lr;
      float bv = bias[col];
#pragma unroll
      for (int r = 0; r < 4; ++r) {
        int row = m0 + wm * 64 + i * 16 + lg * 4 + r;
        float v = acc[i][jj][r] + bv;
        if (MODE == 0) {
          int tt = row >> 4, bb = row & 15;
          C[((size_t)(bb * Td + tt)) * G5H + col] = v;   // gi[b][t][grow]
        } else {
          C[(size_t)row * Vd + col] = v;
        }
      }
    }
}

// ---------------- recurrence kernel v6: AGPR-pinned wave-resident weights ----------------
// One WG per batch, 16 waves. Each wave PERMANENTLY holds 56 fragments (224 regs,
// pinned into AGPRs via opaque asm so the compiler cannot rematerialize):
//   W[0..40)  = w_hh tiles [5*wid, 5*wid+5), 8 k-slices each
//   W[40..48) = Z tile wid
//   W[48..56) = P tile wid
// B-operand packs hi in MFMA col 0 / lo in col 1; result = D[:,0]+D[:,1] via shfl.
__global__ __launch_bounds__(1024, 1) void rnn_kernel(
    const unsigned short* __restrict__ whh_f, const unsigned short* __restrict__ z_f,
    const unsigned short* __restrict__ p_f, const float* __restrict__ b_hh,
    const float* __restrict__ Sm, const float* __restrict__ z_bias,
    const float* __restrict__ gi, const float* __restrict__ goal_ws,
    const float* __restrict__ E_ws, const float* __restrict__ sumE,
    const float* __restrict__ HT0,
    unsigned short* __restrict__ out_all, float* __restrict__ d_out)
{
  __shared__ float gh_lds[1280];
  __shared__ float zd_lds[256];
  __shared__ float hp_lds[256];
  __shared__ float hrow[256];                       // fp32 ht (current)
  __shared__ __align__(16) unsigned short ht_hi[256];
  __shared__ __align__(16) unsigned short ht_lo[256];
  __shared__ __align__(16) unsigned short tp_hi[256];
  __shared__ __align__(16) unsigned short tp_lo[256];
  __shared__ float se_lds[256], gl_lds[256], bh_lds[1280], zb_lds[256];
  __shared__ __align__(16) unsigned short E_lds[Ld * 264];
  __shared__ float a_lds[64], d_lds[64], an_lds[64], au_lds[64];
  __shared__ float sd_lds[4], ref_lds[4];

  const int b = blockIdx.x;
  const int tid = threadIdx.x;
  const int lane = tid & 63, wid = tid >> 6;
  const int lr = lane & 15, lg = lane >> 4;

  // ---- wave-resident weight fragments, pinned in AGPRs ----
  short8v W[56];
  {
    const unsigned short* wb = whh_f + (((size_t)wid * 40) << 9) + (lane << 3);
#pragma unroll
    for (int f = 0; f < 40; ++f) W[f] = *(const short8v*)(wb + ((size_t)f << 9));
    const unsigned short* zb2 = z_f + (((size_t)wid * 8) << 9) + (lane << 3);
#pragma unroll
    for (int f = 0; f < 8; ++f) W[40 + f] = *(const short8v*)(zb2 + ((size_t)f << 9));
    const unsigned short* pb = p_f + (((size_t)wid * 8) << 9) + (lane << 3);
#pragma unroll
    for (int f = 0; f < 8; ++f) W[48 + f] = *(const short8v*)(pb + ((size_t)f << 9));
  }
#pragma unroll
  for (int f = 0; f < 56; ++f) asm volatile("" : "+a"(W[f]));  // opaque: no remat/spill

  // ---- one-time LDS staging ----
  for (int idx = tid; idx < Ld * 256; idx += 1024) {
    int l = idx >> 8, k = idx & 255;
    E_lds[l * 264 + k] = f2bu(E_ws[((size_t)(b * Ld + l) << 8) + k]);
  }
  for (int idx = tid; idx < 1280; idx += 1024) bh_lds[idx] = b_hh[idx];
  if (tid < 256) {
    float se = sumE[(b << 8) + tid];
    se_lds[tid] = se;
    unsigned short hi = f2bu(se);
    tp_hi[tid] = hi; tp_lo[tid] = f2bu(se - bu2f(hi));
    gl_lds[tid] = goal_ws[(b << 8) + tid];
    zb_lds[tid] = z_bias[tid];
    float h0 = HT0[(b << 8) + tid];
    hrow[tid] = h0;
    unsigned short h0h = f2bu(h0);
    ht_hi[tid] = h0h; ht_lo[tid] = f2bu(h0 - bu2f(h0h));
  }
  if (tid < 64) a_lds[tid] = 0.f;
  __syncthreads();

  for (int t = 0; t < Td; ++t) {
    // ---- prefetch gi(t): latency hides under phase A ----
    float pre_ir = 0.f, pre_iu = 0.f, pre_in = 0.f, pre_ig = 0.f, pre_ii = 0.f;
    if (tid < 256) {
      const float* gib = gi + ((size_t)(b * Td + t)) * G5H + tid;
      pre_ir = gib[0];    pre_iu = gib[256];  pre_in = gib[512];
      pre_ig = gib[768];  pre_ii = gib[1024];
    }
    // ========== phase A: gh (5 tiles) + zd (1 tile) per wave, AGPR-resident ==========
    {
      f32x4 acc[5], accz;
#pragma unroll
      for (int i = 0; i < 5; ++i) acc[i] = (f32x4){0.f, 0.f, 0.f, 0.f};
      accz = (f32x4){0.f, 0.f, 0.f, 0.f};
#pragma unroll
      for (int ks = 0; ks < 8; ++ks) {
        short8v bht = {0,0,0,0,0,0,0,0}, btp = {0,0,0,0,0,0,0,0};
        if (lr < 2) {
          bht = *(const short8v*)((lr == 0 ? ht_hi : ht_lo) + ks * 32 + (lg << 3));
          btp = *(const short8v*)((lr == 0 ? tp_hi : tp_lo) + ks * 32 + (lg << 3));
        }
#pragma unroll
        for (int i = 0; i < 5; ++i)
          acc[i] = __builtin_amdgcn_mfma_f32_16x16x32_bf16(W[i * 8 + ks], bht, acc[i], 0, 0, 0);
        accz = __builtin_amdgcn_mfma_f32_16x16x32_bf16(W[40 + ks], btp, accz, 0, 0, 0);
      }
#pragma unroll
      for (int i = 0; i < 5; ++i)
#pragma unroll
        for (int r = 0; r < 4; ++r) {
          float v = acc[i][r] + __shfl_xor(acc[i][r], 1);   // col0(hi)+col1(lo)
          if (lr == 0) gh_lds[(5 * wid + i) * 16 + lg * 4 + r] = v;
        }
#pragma unroll
      for (int r = 0; r < 4; ++r) {
        float v = accz[r] + __shfl_xor(accz[r], 1);
        if (lr == 0) zd_lds[wid * 16 + lg * 4 + r] = v;
      }
    }
    __syncthreads();
    // ========== phase B: gates -> ht2 ==========
    if (tid < 256) {
      int c = tid;
      float hr = gh_lds[c]        + bh_lds[c];
      float hu = gh_lds[256 + c]  + bh_lds[256 + c];
      float hn = gh_lds[512 + c]  + bh_lds[512 + c];
      float hg = gh_lds[768 + c]  + bh_lds[768 + c];
      float hq = gh_lds[1024 + c] + bh_lds[1024 + c];
      float rt = sigm(pre_ir + hr), zt = sigm(pre_iu + hu);
      float st = sigm(pre_ig + hg), qt = sigm(pre_ii + hq);
      float htl = tanhf(pre_in + rt * hn + st * gl_lds[c] + qt * (zd_lds[c] + zb_lds[c]));
      float prev = hrow[c];
      float h2 = htl + zt * (prev - htl);
      hrow[c] = h2;
      unsigned short hi = f2bu(h2);
      ht_hi[c] = hi; ht_lo[c] = f2bu(h2 - bu2f(hi));
    }
    __syncthreads();
    // ========== phase C: h_proj (1 P tile per wave), AGPR-resident ==========
    {
      f32x4 accp = (f32x4){0.f, 0.f, 0.f, 0.f};
#pragma unroll
      for (int ks = 0; ks < 8; ++ks) {
        short8v bht = {0,0,0,0,0,0,0,0};
        if (lr < 2)
          bht = *(const short8v*)((lr == 0 ? ht_hi : ht_lo) + ks * 32 + (lg << 3));
        accp = __builtin_amdgcn_mfma_f32_16x16x32_bf16(W[48 + ks], bht, accp, 0, 0, 0);
      }
#pragma unroll
      for (int r = 0; r < 4; ++r) {
        float v = accp[r] + __shfl_xor(accp[r], 1);
        if (lr == 0) hp_lds[wid * 16 + lg * 4 + r] = v;
      }
    }
    __syncthreads();
    // ========== phase D: E-dots (tid<200) + S-dots (tid 256-447) ==========
    if (tid < 200) {
      int l = tid >> 2, q = tid & 3;
      const unsigned short* er = E_lds + l * 264 + (q << 6);
      const float* hq = hp_lds + (q << 6);
      float p = 0.f;
#pragma unroll 8
      for (int i = 0; i < 32; ++i) {
        unsigned uu = *(const unsigned*)(er + 2 * i);
        float e0 = __uint_as_float(uu << 16);
        float e1 = __uint_as_float(uu & 0xffff0000u);
        p = fmaf(e0, hq[2 * i], p);
        p = fmaf(e1, hq[2 * i + 1], p);
      }
      p += __shfl_xor(p, 1); p += __shfl_xor(p, 2);
      if (q == 0) d_lds[l] = p;
    } else if (tid >= 256 && tid < 448) {           // S dots (needs hrow from phase B)
      int w = (tid - 256) >> 6, ln = tid & 63;
      float4 sv = *(const float4*)(Sm + (w << 8) + (ln << 2));
      float4 hv = *(const float4*)(hrow + (ln << 2));
      float p = sv.x * hv.x + sv.y * hv.y + sv.z * hv.z + sv.w * hv.w;
      p += __shfl_xor(p, 1);  p += __shfl_xor(p, 2);  p += __shfl_xor(p, 4);
      p += __shfl_xor(p, 8);  p += __shfl_xor(p, 16); p += __shfl_xor(p, 32);
      if (ln == 0) sd_lds[w] = p;
    }
    __syncthreads();
    // ========== phase E: alpha_n / alpha_u + ref softmax ==========
    if (tid < 128) {
      int which = tid >> 6;
      int l = tid & 63;
      float dv;
      if (which == 0) dv = (l < Ld) ? 2.0f * (1.f - a_lds[l]) * d_lds[l] : -3.4e38f;
      else            dv = (l < Ld) ? 2.0f * a_lds[l] * d_lds[l]         : -3.4e38f;
      float m = dv;
      m = fmaxf(m, __shfl_xor(m, 1));  m = fmaxf(m, __shfl_xor(m, 2));
      m = fmaxf(m, __shfl_xor(m, 4));  m = fmaxf(m, __shfl_xor(m, 8));
      m = fmaxf(m, __shfl_xor(m, 16)); m = fmaxf(m, __shfl_xor(m, 32));
      float e = (l < Ld) ? __expf(dv - m) : 0.f;
      float ss = e;
      ss += __shfl_xor(ss, 1);  ss += __shfl_xor(ss, 2);  ss += __shfl_xor(ss, 4);
      ss += __shfl_xor(ss, 8);  ss += __shfl_xor(ss, 16); ss += __shfl_xor(ss, 32);
      float al = e / ss;
      if (which == 0) an_lds[l] = al; else au_lds[l] = al;
    } else if (tid == 192) {                        // ref = softmax(BETA*sd)
      float s0 = 5.0f * sd_lds[0], s1 = 5.0f * sd_lds[1], s2 = 5.0f * sd_lds[2];
      float m = fmaxf(s0, fmaxf(s1, s2));
      float e0 = __expf(s0 - m), e1 = __expf(s1 - m), e2 = __expf(s2 - m);
      float inv = 1.f / (e0 + e1 + e2);
      ref_lds[0] = e0 * inv; ref_lds[1] = e1 * inv; ref_lds[2] = e2 * inv;
    }
    __syncthreads();
    // ========== phase F: c_n, c_u, out, tmp(t+1) ==========
    if (tid < 256) {
      int k = tid;
      float accn = 0.f, accu = 0.f, acct = 0.f;
#pragma unroll 10
      for (int l = 0; l < Ld; ++l) {
        float e = bu2f(E_lds[l * 264 + k]);
        accn = fmaf(an_lds[l], e, accn);
        accu = fmaf(au_lds[l], e, accu);
        acct = fmaf(a_lds[l], e, acct);            // a BEFORE this step's update
      }
      float outv = ref_lds[0] * hp_lds[k] + ref_lds[1] * accn + ref_lds[2] * accu;
      out_all[(((b << 7) + t) << 8) + k] = f2bu(outv);
      float tn = se_lds[k] - acct;                 // tmp(t+1) = sum((1-a)*E)
      unsigned short th = f2bu(tn);
      tp_hi[k] = th; tp_lo[k] = f2bu(tn - bu2f(th));
      if (t == Td - 1) {
        d_out[(size_t)65536000 + (b << 8) + k] = hrow[k];
        for (int l = 0; l < Ld; ++l) {             // E_new = (1-a_pre)*E (fp32 source)
          size_t o = ((size_t)(b * Ld + l) << 8) + k;
          d_out[(size_t)65540896 + o] = (1.f - a_lds[l]) * E_ws[o];
        }
      }
    }
    __syncthreads();
    // ========== phase G: a update ==========
    if (tid < Ld) {
      float na = a_lds[tid] + ref_lds[1] * an_lds[tid];
      a_lds[tid] = na;
      if (t == Td - 1) d_out[(size_t)65540096 + b * Ld + tid] = na;
    }
    __syncthreads();
  }
}

// ---------------- host launcher ----------------
extern "C" void kernel_launch(void* const* d_in, const int* in_sizes, int n_in,
                              void* d_out, int out_size, void* d_ws, size_t ws_size,
                              hipStream_t stream)
{
  const int*   recipe = (const int*)d_in[0];
  const int*   g      = (const int*)d_in[1];
  const int*   ingr   = (const int*)d_in[2];
  const float* wv     = (const float*)d_in[3];
  const float* w_ih   = (const float*)d_in[4];
  const float* w_hh   = (const float*)d_in[5];
  const float* b_ih   = (const float*)d_in[6];
  const float* b_hh   = (const float*)d_in[7];
  const float* Z      = (const float*)d_in[8];
  const float* Y      = (const float*)d_in[9];
  const float* Ug     = (const float*)d_in[10];
  const float* z_bias = (const float*)d_in[11];
  const float* y_bias = (const float*)d_in[12];
  const float* S      = (const float*)d_in[13];
  const float* P      = (const float*)d_in[14];
  const float* fcW    = (const float*)d_in[15];
  const float* fcb    = (const float*)d_in[16];
  float* out = (float*)d_out;
  char* ws = (char*)d_ws;

  size_t off = 0;
  unsigned short* wv_b     = (unsigned short*)(ws + off);  off += 16384000;
  unsigned short* wih_b    = (unsigned short*)(ws + off);  off += 655360;
  unsigned short* fcw_b    = (unsigned short*)(ws + off);  off += 16384000;
  unsigned short* whh_f    = (unsigned short*)(ws + off);  off += 655360;
  unsigned short* z_f      = (unsigned short*)(ws + off);  off += 131072;
  unsigned short* p_f      = (unsigned short*)(ws + off);  off += 131072;
  float* gi_ws             = (float*)(ws + off);           off += 10485760;
  float* E_ws              = (float*)(ws + off);           off += 819200;
  float* sumE              = (float*)(ws + off);           off += 16384;
  float* goal_ws           = (float*)(ws + off);           off += 16384;
  float* HT0               = (float*)(ws + off);           off += 16384;
  unsigned short* out_all  = (unsigned short*)(ws + off);  off += 1048576;

  conv_kernel<<<4096, 256, 0, stream>>>(wv, w_ih, fcW, w_hh, Z, P,
                                        wv_b, wih_b, fcw_b, whh_f, z_f, p_f);
  prep_kernel<<<16, 256, 0, stream>>>(g, ingr, wv, Ug, Y, y_bias,
                                      E_ws, sumE, goal_ws, HT0);
  gemm_bf16<0><<<dim3(16, 10), 256, 0, stream>>>(wv_b, wih_b, recipe, b_ih, gi_ws);
  rnn_kernel<<<16, 1024, 0, stream>>>(whh_f, z_f, p_f, b_hh, S, z_bias,
                                      gi_ws, goal_ws, E_ws, sumE, HT0,
                                      out_all, out);
  gemm_bf16<1><<<dim3(16, 250), 256, 0, stream>>>(out_all, fcw_b, nullptr, fcb, out);
}

// Round 7
// 1703.890 us; speedup vs baseline: 2.6238x; 2.1982x over previous
//
#include <hip/hip_runtime.h>

// ---------------- problem constants ----------------
#define Hd   256
#define Bd   16
#define Td   128
#define Ld   50
#define Vd   32000
#define G5H  1280     // 5*H

typedef __attribute__((ext_vector_type(8))) short short8v;  // 8 bf16 (4 VGPRs)
typedef __attribute__((ext_vector_type(4))) float f32x4;

__device__ __forceinline__ unsigned short f2bu(float f) {   // f32 -> bf16 bits (RNE)
  unsigned u = __float_as_uint(f);
  unsigned r = (u + 0x7fffu + ((u >> 16) & 1u)) >> 16;
  return (unsigned short)r;
}
__device__ __forceinline__ float bu2f(unsigned short b) {
  return __uint_as_float(((unsigned)b) << 16);
}
__device__ __forceinline__ float sigm(float x) { return 1.f / (1.f + __expf(-x)); }
// agent-scope (MALL-direct) relaxed ops — bypass per-XCD L1/L2
__device__ __forceinline__ void st_dev(float* p, float v) {
  __hip_atomic_store(p, v, __ATOMIC_RELAXED, __HIP_MEMORY_SCOPE_AGENT);
}
__device__ __forceinline__ float ld_dev(const float* p) {
  return __hip_atomic_load((float*)p, __ATOMIC_RELAXED, __HIP_MEMORY_SCOPE_AGENT);
}
__device__ __forceinline__ void st_devu(unsigned* p, unsigned v) {
  __hip_atomic_store(p, v, __ATOMIC_RELAXED, __HIP_MEMORY_SCOPE_AGENT);
}
__device__ __forceinline__ unsigned ld_devu(const unsigned* p) {
  return __hip_atomic_load((unsigned*)p, __ATOMIC_RELAXED, __HIP_MEMORY_SCOPE_AGENT);
}

// ---------------- fp32 -> bf16 conversion + MFMA fragment packing ----------------
// Plain bf16 copies: wv, w_ih, fcW. Fragment-ordered: w_hh, Z, P.
// Fragment (T,ks) = 512 shorts; lane L reads [frag*512 + L*8) =
// mat[T*16 + (L&15)][ks*32 + (L>>4)*8 .. +8).
__global__ __launch_bounds__(256) void conv_kernel(
    const float* __restrict__ wv, const float* __restrict__ w_ih,
    const float* __restrict__ fcW, const float* __restrict__ w_hh,
    const float* __restrict__ Zm, const float* __restrict__ Pm,
    unsigned short* __restrict__ wv_b, unsigned short* __restrict__ wih_b,
    unsigned short* __restrict__ fcw_b, unsigned short* __restrict__ whh_f,
    unsigned short* __restrict__ z_f, unsigned short* __restrict__ p_f)
{
  const long N0 = 2048000, N1 = N0 + 81920, N2 = N1 + 2048000;
  const long NW = 81920, NZ = 16384, NP = 16384;         // frag float4-groups
  const long N5 = N2 + NW + NZ + NP;
  for (long idx = (long)blockIdx.x * blockDim.x + threadIdx.x; idx < N5;
       idx += (long)gridDim.x * blockDim.x) {
    if (idx < N2) {                                      // plain copies
      const float* src; unsigned short* dst; long off;
      if      (idx < N0) { src = wv;   dst = wv_b;  off = idx; }
      else if (idx < N1) { src = w_ih; dst = wih_b; off = idx - N0; }
      else               { src = fcW;  dst = fcw_b; off = idx - N1; }
      float4 v = *(const float4*)(src + off * 4);
      ushort4 o;
      o.x = f2bu(v.x); o.y = f2bu(v.y); o.z = f2bu(v.z); o.w = f2bu(v.w);
      *(ushort4*)(dst + off * 4) = o;
    } else {                                             // fragment packing
      long u = idx - N2;
      const float* src; unsigned short* dst;
      if      (u < NW)      { src = w_hh; dst = whh_f; }
      else if (u < NW + NZ) { src = Zm;   dst = z_f;  u -= NW; }
      else                  { src = Pm;   dst = p_f;  u -= NW + NZ; }
      long frag = u >> 7;                 // 128 float4-groups per 512-short frag
      int g128 = (int)(u & 127);
      int lane = g128 >> 1, e0 = (g128 & 1) * 4;
      long T = frag >> 3; int ks = (int)(frag & 7);
      int lr = lane & 15, lg = lane >> 4;
      float4 v = *(const float4*)(src + (T * 16 + lr) * 256 + ks * 32 + lg * 8 + e0);
      ushort4 o;
      o.x = f2bu(v.x); o.y = f2bu(v.y); o.z = f2bu(v.z); o.w = f2bu(v.w);
      *(ushort4*)(dst + u * 4) = o;
    }
  }
}

// ---------------- per-batch prep: goal embed, ht0, goal_term, E, sumE ----------------
__global__ __launch_bounds__(256) void prep_kernel(
    const int* __restrict__ g, const int* __restrict__ ingr,
    const float* __restrict__ wv, const float* __restrict__ Ug,
    const float* __restrict__ Ym, const float* __restrict__ yb,
    float* __restrict__ E_ws, float* __restrict__ sumE,
    float* __restrict__ goal_ws, float* __restrict__ HT0)
{
  __shared__ float ge[256];
  const int b = blockIdx.x, tid = threadIdx.x;
  float s = 0.f;
  for (int i = 0; i < 8; ++i) s += wv[((size_t)g[(b << 3) + i] << 8) + tid];
  ge[tid] = s;
  __syncthreads();
  float h0 = 0.f, gt = 0.f;
  const float* ur = Ug + (tid << 8);
  const float* yr = Ym + (tid << 8);
#pragma unroll 8
  for (int k = 0; k < Hd; k += 4) {
    float4 gv = *(const float4*)(ge + k);
    float4 uv = *(const float4*)(ur + k);
    float4 yv = *(const float4*)(yr + k);
    h0 = fmaf(gv.x, uv.x, h0); h0 = fmaf(gv.y, uv.y, h0);
    h0 = fmaf(gv.z, uv.z, h0); h0 = fmaf(gv.w, uv.w, h0);
    gt = fmaf(gv.x, yv.x, gt); gt = fmaf(gv.y, yv.y, gt);
    gt = fmaf(gv.z, yv.z, gt); gt = fmaf(gv.w, yv.w, gt);
  }
  HT0[(b << 8) + tid] = h0;                    // [b][c]
  goal_ws[(b << 8) + tid] = gt + yb[tid];      // [b][c]
  float se = 0.f;
  for (int l = 0; l < Ld; ++l) {
    float v = wv[((size_t)ingr[b * Ld + l] << 8) + tid];
    E_ws[((size_t)(b * Ld + l) << 8) + tid] = v;
    se += v;
  }
  sumE[(b << 8) + tid] = se;                   // [b][k]
}

// ---------------- bf16 MFMA GEMM (128x128 tile, K=256), two epilogues ----------------
template <int MODE>
__global__ __launch_bounds__(256) void gemm_bf16(
    const unsigned short* __restrict__ A, const unsigned short* __restrict__ Bmat,
    const int* __restrict__ ridx, const float* __restrict__ bias,
    float* __restrict__ C)
{
  __shared__ unsigned short As[128 * 64];
  __shared__ unsigned short Bs[128 * 64];
  const int tid = threadIdx.x;
  const int m0 = blockIdx.x << 7, n0 = blockIdx.y << 7;
  const int wave = tid >> 6, lane = tid & 63;
  const int wm = wave >> 1, wn = wave & 1;
  const int lr = lane & 15, lg = lane >> 4;

  f32x4 acc[4][4];
#pragma unroll
  for (int i = 0; i < 4; ++i)
#pragma unroll
    for (int jj = 0; jj < 4; ++jj) acc[i][jj] = (f32x4){0.f, 0.f, 0.f, 0.f};

  const int srow = tid >> 1, shalf = tid & 1;
  const unsigned short* arow;
  {
    int gm = m0 + srow;
    if (MODE == 0) {
      int tt = gm >> 4, bb = gm & 15;
      arow = A + (size_t)ridx[bb * Td + tt] * Hd;
    } else {
      arow = A + (size_t)gm * Hd;
    }
  }
  const unsigned short* brow = Bmat + (size_t)(n0 + srow) * Hd;

  for (int k0 = 0; k0 < Hd; k0 += 64) {
#pragma unroll
    for (int c = 0; c < 4; ++c) {
      int k = shalf * 32 + c * 8;
      uint4 va = *(const uint4*)(arow + k0 + k);
      uint4 vb = *(const uint4*)(brow + k0 + k);
      int byo = (srow << 7) + ((k << 1) ^ ((srow & 7) << 4));  // XOR swizzle
      *(uint4*)((char*)As + byo) = va;
      *(uint4*)((char*)Bs + byo) = vb;
    }
    __syncthreads();
#pragma unroll
    for (int kk = 0; kk < 2; ++kk) {
      short8v af[4], bfr[4];
      const int kb = kk * 32 + lg * 8;
#pragma unroll
      for (int i = 0; i < 4; ++i) {
        int ar = wm * 64 + i * 16 + lr;
        af[i] = *(const short8v*)((const char*)As + (ar << 7) + ((kb << 1) ^ ((ar & 7) << 4)));
        int br = wn * 64 + i * 16 + lr;
        bfr[i] = *(const short8v*)((const char*)Bs + (br << 7) + ((kb << 1) ^ ((br & 7) << 4)));
      }
#pragma unroll
      for (int i = 0; i < 4; ++i)
#pragma unroll
        for (int jj = 0; jj < 4; ++jj)
          acc[i][jj] = __builtin_amdgcn_mfma_f32_16x16x32_bf16(af[i], bfr[jj], acc[i][jj], 0, 0, 0);
    }
    __syncthreads();
  }
#pragma unroll
  for (int i = 0; i < 4; ++i)
#pragma unroll
    for (int jj = 0; jj < 4; ++jj) {
      int col = n0 + wn * 64 + jj * 16 + lr;
      float bv = bias[col];
#pragma unroll
      for (int r = 0; r < 4; ++r) {
        int row = m0 + wm * 64 + i * 16 + lg * 4 + r;
        float v = acc[i][jj][r] + bv;
        if (MODE == 0) {
          int tt = row >> 4, bb = row & 15;
          C[((size_t)(bb * Td + tt)) * G5H + col] = v;   // gi[b][t][grow]
        } else {
          C[(size_t)row * Vd + col] = v;
        }
      }
    }
}

// ---------------- recurrence v7: 8 WGs per batch, LDS-resident weight slices ----------------
// WG (b, j=0..7) owns h-cols [32j..32j+32): w_hh rows {g*256+slice} (80KB),
// Z rows slice (16KB), P COLUMN-slice (16KB, = frags (T, ks=j)), E[b] (26KB).
// Per step: MFMA gh+zd -> gates -> ht2 slice + h_proj partial -> publish (MALL)
// -> poll 8 flags -> gather ht2 full + sum h_proj partials -> replicated attention.
// ONE rendezvous per step; payload double-buffered; flags monotonic.
#define RNN_SMEM 149056
__global__ __launch_bounds__(256, 1) void rnn_kernel(
    const unsigned short* __restrict__ whh_f, const unsigned short* __restrict__ z_f,
    const unsigned short* __restrict__ p_f, const float* __restrict__ b_hh,
    const float* __restrict__ Sm, const float* __restrict__ z_bias,
    const float* __restrict__ gi, const float* __restrict__ goal_ws,
    const float* __restrict__ E_ws, const float* __restrict__ sumE,
    const float* __restrict__ HT0,
    unsigned short* __restrict__ out_all, float* __restrict__ d_out,
    float* __restrict__ XB, unsigned* __restrict__ FL)
{
  extern __shared__ char smem[];
  unsigned short* w_lds = (unsigned short*)(smem);            // 10 tiles*8ks*512
  unsigned short* z_lds = (unsigned short*)(smem + 81920);    // 2*8*512
  unsigned short* p_lds = (unsigned short*)(smem + 98304);    // 16*512 (ks=j)
  unsigned short* E_lds = (unsigned short*)(smem + 114688);   // 50*264
  float* hrow  = (float*)(smem + 141088);   // 256 fp32 ht (current, full)
  float* hp    = (float*)(smem + 142112);   // 256 h_proj (full, summed)
  float* gh    = (float*)(smem + 143136);   // 160 (g*32+cl)
  float* zd    = (float*)(smem + 143776);   // 32
  float* se    = (float*)(smem + 143904);   // 256
  float* gl    = (float*)(smem + 144928);   // 32 (goal_term slice)
  float* bh    = (float*)(smem + 145056);   // 160
  float* zb    = (float*)(smem + 145696);   // 32
  float* a_l   = (float*)(smem + 145824);   // 64
  float* d_l   = (float*)(smem + 146080);   // 64
  float* an_l  = (float*)(smem + 146336);   // 64
  float* au_l  = (float*)(smem + 146592);   // 64
  float* sd    = (float*)(smem + 146848);   // 4
  float* refl  = (float*)(smem + 146864);   // 4
  unsigned short* ht_hi = (unsigned short*)(smem + 146880);   // 256
  unsigned short* ht_lo = (unsigned short*)(smem + 147392);   // 256
  unsigned short* tp_hi = (unsigned short*)(smem + 147904);   // 256
  unsigned short* tp_lo = (unsigned short*)(smem + 148416);   // 256
  unsigned short* hs_hi = (unsigned short*)(smem + 148928);   // 32 (ht2 slice)
  unsigned short* hs_lo = (unsigned short*)(smem + 148992);   // 32

  const int b  = blockIdx.x >> 3;
  const int j  = blockIdx.x & 7;
  const int hc0 = j << 5;
  const int tid = threadIdx.x;
  const int lane = tid & 63, wid = tid >> 6;
  const int lr = lane & 15, lg = lane >> 4;
  unsigned* FLb = FL + (b << 4);

  // ---- one-time staging ----
  for (int idx = tid; idx < 5120; idx += 256) {        // w_hh slice (uint4 units)
    int f = idx >> 6, e = idx & 63;
    int q = f >> 3, ks = f & 7;
    int T = (q >> 1) * 16 + 2 * j + (q & 1);
    *(uint4*)(w_lds + ((size_t)f << 9) + e * 8) =
        *(const uint4*)(whh_f + (((size_t)T * 8 + ks) << 9) + e * 8);
  }
  for (int idx = tid; idx < 1024; idx += 256) {        // Z slice
    int f = idx >> 6, e = idx & 63;
    int q = f >> 3, ks = f & 7;
    int T = 2 * j + q;
    *(uint4*)(z_lds + ((size_t)f << 9) + e * 8) =
        *(const uint4*)(z_f + (((size_t)T * 8 + ks) << 9) + e * 8);
  }
  for (int idx = tid; idx < 1024; idx += 256) {        // P column-slice (ks=j)
    int f = idx >> 6, e = idx & 63;
    *(uint4*)(p_lds + ((size_t)f << 9) + e * 8) =
        *(const uint4*)(p_f + (((size_t)f * 8 + j) << 9) + e * 8);
  }
  for (int idx = tid; idx < Ld * 256; idx += 256) {    // E bf16
    int l = idx >> 8, k = idx & 255;
    E_lds[l * 264 + k] = f2bu(E_ws[((size_t)(b * Ld + l) << 8) + k]);
  }
  if (tid < 160) bh[tid] = b_hh[((tid >> 5) << 8) + hc0 + (tid & 31)];
  if (tid < 32) {
    gl[tid] = goal_ws[(b << 8) + hc0 + tid];
    zb[tid] = z_bias[hc0 + tid];
  }
  if (tid < 256) {
    float s0 = sumE[(b << 8) + tid];
    se[tid] = s0;
    unsigned short hi = f2bu(s0);
    tp_hi[tid] = hi; tp_lo[tid] = f2bu(s0 - bu2f(hi));
    float h0 = HT0[(b << 8) + tid];
    hrow[tid] = h0;
    unsigned short hh = f2bu(h0);
    ht_hi[tid] = hh; ht_lo[tid] = f2bu(h0 - bu2f(hh));
  }
  if (tid < 64) a_l[tid] = 0.f;
  __syncthreads();

  for (int t = 0; t < Td; ++t) {
    float* pub = XB + ((size_t)(((t & 1) * 16 + b) * 8 + j)) * 288;
    const float* XBr = XB + ((size_t)(((t & 1) * 16 + b) * 8)) * 288;
    // ---- gi prefetch (tid<32), hides under A1 ----
    float g_ir = 0.f, g_iu = 0.f, g_in = 0.f, g_ig = 0.f, g_ii = 0.f;
    if (tid < 32) {
      const float* gib = gi + ((size_t)(b * Td + t)) * G5H + hc0 + tid;
      g_ir = gib[0];    g_iu = gib[256];  g_in = gib[512];
      g_ig = gib[768];  g_ii = gib[1024];
    }
    // ========== A1: gh (10 tiles) + zd (2 tiles), 3 tiles/wave ==========
#pragma unroll
    for (int ti = 0; ti < 3; ++ti) {
      int q = wid * 3 + ti;
      const unsigned short* base = (q < 10) ? (w_lds + ((size_t)(q * 8) << 9))
                                            : (z_lds + ((size_t)((q - 10) * 8) << 9));
      const unsigned short* shi = (q < 10) ? ht_hi : tp_hi;
      const unsigned short* slo = (q < 10) ? ht_lo : tp_lo;
      f32x4 acc = (f32x4){0.f, 0.f, 0.f, 0.f};
#pragma unroll
      for (int ks = 0; ks < 8; ++ks) {
        short8v av = *(const short8v*)(base + ((size_t)ks << 9) + (lane << 3));
        short8v bv = (short8v){0, 0, 0, 0, 0, 0, 0, 0};
        if (lr < 2)
          bv = *(const short8v*)((lr == 0 ? shi : slo) + ks * 32 + (lg << 3));
        acc = __builtin_amdgcn_mfma_f32_16x16x32_bf16(av, bv, acc, 0, 0, 0);
      }
#pragma unroll
      for (int r = 0; r < 4; ++r) {
        float v = acc[r] + __shfl_xor(acc[r], 1);        // col0(hi)+col1(lo)
        if (lr == 0) {
          int row = q * 16 + lg * 4 + r;
          if (q < 10) gh[row] = v; else zd[row - 160] = v;
        }
      }
    }
    __syncthreads();
    // ========== A2: gates -> ht2 slice (tid<32) + publish slice ==========
    if (tid < 32) {
      int cl = tid;
      float hr = gh[cl]       + bh[cl];
      float hu = gh[32 + cl]  + bh[32 + cl];
      float hn = gh[64 + cl]  + bh[64 + cl];
      float hg = gh[96 + cl]  + bh[96 + cl];
      float hq = gh[128 + cl] + bh[128 + cl];
      float rt = sigm(g_ir + hr), zt = sigm(g_iu + hu);
      float st = sigm(g_ig + hg), qt = sigm(g_ii + hq);
      float htl = tanhf(g_in + rt * hn + st * gl[cl] + qt * (zd[cl] + zb[cl]));
      float prev = hrow[hc0 + cl];
      float h2 = htl + zt * (prev - htl);
      unsigned short hi = f2bu(h2);
      hs_hi[cl] = hi; hs_lo[cl] = f2bu(h2 - bu2f(hi));
      st_dev(pub + cl, h2);                              // publish ht2 slice
    }
    __syncthreads();
    // ========== A3: h_proj partial (16 tiles, K=32) -> publish ==========
#pragma unroll
    for (int ti = 0; ti < 4; ++ti) {
      int q = wid * 4 + ti;
      short8v av = *(const short8v*)(p_lds + ((size_t)q << 9) + (lane << 3));
      short8v bv = (short8v){0, 0, 0, 0, 0, 0, 0, 0};
      if (lr < 2)
        bv = *(const short8v*)((lr == 0 ? hs_hi : hs_lo) + (lg << 3));
      f32x4 acc = (f32x4){0.f, 0.f, 0.f, 0.f};
      acc = __builtin_amdgcn_mfma_f32_16x16x32_bf16(av, bv, acc, 0, 0, 0);
#pragma unroll
      for (int r = 0; r < 4; ++r) {
        float v = acc[r] + __shfl_xor(acc[r], 1);
        if (lr == 0) st_dev(pub + 32 + q * 16 + lg * 4 + r, v);
      }
    }
    // ---- flag release: all payload stores retired (per-wave vmcnt + barrier) ----
    asm volatile("s_waitcnt vmcnt(0)" ::: "memory");
    __syncthreads();
    if (tid == 0) st_devu(FLb + j, (unsigned)(t + 1));
    // ---- poll all 8 flags ----
    if (tid < 64) {
      unsigned tgt = (unsigned)(t + 1);
      int guard = 0;
      while (1) {
        unsigned v = (lane < 8) ? ld_devu(FLb + lane) : tgt;
        if (__all((int)(v >= tgt))) break;
        __builtin_amdgcn_s_sleep(1);
        if (++guard > (1 << 20)) break;
      }
    }
    __syncthreads();
    // ========== GATH: full ht2 + h_proj (deterministic order) ==========
    {
      int c = tid;
      float v = ld_dev(XBr + (size_t)(c >> 5) * 288 + (c & 31));
      hrow[c] = v;
      unsigned short hi = f2bu(v);
      ht_hi[c] = hi; ht_lo[c] = f2bu(v - bu2f(hi));
      float s0 = 0.f;
#pragma unroll
      for (int js = 0; js < 8; ++js)
        s0 += ld_dev(XBr + (size_t)js * 288 + 32 + c);
      hp[c] = s0;
    }
    __syncthreads();
    // ========== D1: S-dots (replicated) ==========
    if (tid < 192) {
      int w = tid >> 6;
      float4 sv = *(const float4*)(Sm + (w << 8) + ((tid & 63) << 2));
      float4 hv = *(const float4*)(hrow + ((tid & 63) << 2));
      float p = sv.x * hv.x + sv.y * hv.y + sv.z * hv.z + sv.w * hv.w;
      p += __shfl_xor(p, 1);  p += __shfl_xor(p, 2);  p += __shfl_xor(p, 4);
      p += __shfl_xor(p, 8);  p += __shfl_xor(p, 16); p += __shfl_xor(p, 32);
      if ((tid & 63) == 0) sd[w] = p;
    }
    __syncthreads();
    // ========== D2: E-dots + ref softmax ==========
    if (tid < 200) {
      int l = tid >> 2, q = tid & 3;
      const unsigned short* er = E_lds + l * 264 + (q << 6);
      const float* hq = hp + (q << 6);
      float p = 0.f;
#pragma unroll 8
      for (int i = 0; i < 32; ++i) {
        unsigned uu = *(const unsigned*)(er + 2 * i);
        float e0 = __uint_as_float(uu << 16);
        float e1 = __uint_as_float(uu & 0xffff0000u);
        p = fmaf(e0, hq[2 * i], p);
        p = fmaf(e1, hq[2 * i + 1], p);
      }
      p += __shfl_xor(p, 1); p += __shfl_xor(p, 2);
      if (q == 0) d_l[l] = p;
    } else if (tid == 224) {                        // ref = softmax(BETA*sd)
      float s0 = 5.0f * sd[0], s1 = 5.0f * sd[1], s2 = 5.0f * sd[2];
      float m = fmaxf(s0, fmaxf(s1, s2));
      float e0 = __expf(s0 - m), e1 = __expf(s1 - m), e2 = __expf(s2 - m);
      float inv = 1.f / (e0 + e1 + e2);
      refl[0] = e0 * inv; refl[1] = e1 * inv; refl[2] = e2 * inv;
    }
    __syncthreads();
    // ========== E: alpha_n / alpha_u ==========
    if (tid < 128) {
      int which = tid >> 6;
      int l = tid & 63;
      float dv;
      if (which == 0) dv = (l < Ld) ? 2.0f * (1.f - a_l[l]) * d_l[l] : -3.4e38f;
      else            dv = (l < Ld) ? 2.0f * a_l[l] * d_l[l]         : -3.4e38f;
      float m = dv;
      m = fmaxf(m, __shfl_xor(m, 1));  m = fmaxf(m, __shfl_xor(m, 2));
      m = fmaxf(m, __shfl_xor(m, 4));  m = fmaxf(m, __shfl_xor(m, 8));
      m = fmaxf(m, __shfl_xor(m, 16)); m = fmaxf(m, __shfl_xor(m, 32));
      float e = (l < Ld) ? __expf(dv - m) : 0.f;
      float ss = e;
      ss += __shfl_xor(ss, 1);  ss += __shfl_xor(ss, 2);  ss += __shfl_xor(ss, 4);
      ss += __shfl_xor(ss, 8);  ss += __shfl_xor(ss, 16); ss += __shfl_xor(ss, 32);
      float al = e / ss;
      if (which == 0) an_l[l] = al; else au_l[l] = al;
    }
    __syncthreads();
    // ========== F: c_n, c_u, out, tmp(t+1)  (replicated; WG0 stores) ==========
    {
      int k = tid;
      float accn = 0.f, accu = 0.f, acct = 0.f;
#pragma unroll 10
      for (int l = 0; l < Ld; ++l) {
        float e = bu2f(E_lds[l * 264 + k]);
        accn = fmaf(an_l[l], e, accn);
        accu = fmaf(au_l[l], e, accu);
        acct = fmaf(a_l[l], e, acct);              // a BEFORE this step's update
      }
      float outv = refl[0] * hp[k] + refl[1] * accn + refl[2] * accu;
      float tn = se[k] - acct;                     // tmp(t+1) = sum((1-a)*E)
      unsigned short th = f2bu(tn);
      tp_hi[k] = th; tp_lo[k] = f2bu(tn - bu2f(th));
      if (j == 0) {
        out_all[(((b << 7) + t) << 8) + k] = f2bu(outv);
        if (t == Td - 1) {
          d_out[(size_t)65536000 + (b << 8) + k] = hrow[k];
          for (int l = 0; l < Ld; ++l) {           // E_new = (1-a_pre)*E
            size_t o = ((size_t)(b * Ld + l) << 8) + k;
            d_out[(size_t)65540896 + o] = (1.f - a_l[l]) * E_ws[o];
          }
        }
      }
    }
    __syncthreads();
    // ========== G: a update ==========
    if (tid < Ld) {
      float na = a_l[tid] + refl[1] * an_l[tid];
      a_l[tid] = na;
      if (t == Td - 1 && j == 0) d_out[(size_t)65540096 + b * Ld + tid] = na;
    }
    __syncthreads();
  }
}

// ---------------- host launcher ----------------
extern "C" void kernel_launch(void* const* d_in, const int* in_sizes, int n_in,
                              void* d_out, int out_size, void* d_ws, size_t ws_size,
                              hipStream_t stream)
{
  const int*   recipe = (const int*)d_in[0];
  const int*   g      = (const int*)d_in[1];
  const int*   ingr   = (const int*)d_in[2];
  const float* wv     = (const float*)d_in[3];
  const float* w_ih   = (const float*)d_in[4];
  const float* w_hh   = (const float*)d_in[5];
  const float* b_ih   = (const float*)d_in[6];
  const float* b_hh   = (const float*)d_in[7];
  const float* Z      = (const float*)d_in[8];
  const float* Y      = (const float*)d_in[9];
  const float* Ug     = (const float*)d_in[10];
  const float* z_bias = (const float*)d_in[11];
  const float* y_bias = (const float*)d_in[12];
  const float* S      = (const float*)d_in[13];
  const float* P      = (const float*)d_in[14];
  const float* fcW    = (const float*)d_in[15];
  const float* fcb    = (const float*)d_in[16];
  float* out = (float*)d_out;
  char* ws = (char*)d_ws;

  size_t off = 0;
  unsigned* FL             = (unsigned*)(ws + off);        off += 1024;
  float* XB                = (float*)(ws + off);           off += 294912;
  unsigned short* wv_b     = (unsigned short*)(ws + off);  off += 16384000;
  unsigned short* wih_b    = (unsigned short*)(ws + off);  off += 655360;
  unsigned short* fcw_b    = (unsigned short*)(ws + off);  off += 16384000;
  unsigned short* whh_f    = (unsigned short*)(ws + off);  off += 655360;
  unsigned short* z_f      = (unsigned short*)(ws + off);  off += 131072;
  unsigned short* p_f      = (unsigned short*)(ws + off);  off += 131072;
  float* gi_ws             = (float*)(ws + off);           off += 10485760;
  float* E_ws              = (float*)(ws + off);           off += 819200;
  float* sumE              = (float*)(ws + off);           off += 16384;
  float* goal_ws           = (float*)(ws + off);           off += 16384;
  float* HT0               = (float*)(ws + off);           off += 16384;
  unsigned short* out_all  = (unsigned short*)(ws + off);  off += 1048576;

  hipMemsetAsync(FL, 0, 1024, stream);
  conv_kernel<<<4096, 256, 0, stream>>>(wv, w_ih, fcW, w_hh, Z, P,
                                        wv_b, wih_b, fcw_b, whh_f, z_f, p_f);
  prep_kernel<<<16, 256, 0, stream>>>(g, ingr, wv, Ug, Y, y_bias,
                                      E_ws, sumE, goal_ws, HT0);
  gemm_bf16<0><<<dim3(16, 10), 256, 0, stream>>>(wv_b, wih_b, recipe, b_ih, gi_ws);
  hipFuncSetAttribute((const void*)rnn_kernel,
                      hipFuncAttributeMaxDynamicSharedMemorySize, RNN_SMEM);
  rnn_kernel<<<128, 256, RNN_SMEM, stream>>>(whh_f, z_f, p_f, b_hh, S, z_bias,
                                             gi_ws, goal_ws, E_ws, sumE, HT0,
                                             out_all, out, XB, FL);
  gemm_bf16<1><<<dim3(16, 250), 256, 0, stream>>>(out_all, fcw_b, nullptr, fcb, out);
}